// Round 2
// baseline (272.039 us; speedup 1.0000x reference)
//
#include <hip/hip_runtime.h>

#define SEQ 4096
#define DM 1024
#define DS 64
#define KS 64

#define TCH 64             // channels per block
#define STEP 64            // outputs per step
#define NSTEP 8            // steps per block
#define OUTB (STEP*NSTEP)  // 512 outputs per block
#define R 8                // outputs per thread per step
#define CAP 192            // circular row capacity (48 KB)

// ---------------------------------------------------------------------------
// async global->LDS helper (16B per lane; LDS dest = wave-uniform base + lane*16)
// ---------------------------------------------------------------------------
typedef const __attribute__((address_space(1))) void* gas_ptr;
typedef __attribute__((address_space(3))) void* las_ptr;
__device__ __forceinline__ void async_cp16(const void* g, void* s) {
    __builtin_amdgcn_global_load_lds((gas_ptr)g, (las_ptr)s, 16, 0, 0);
}

// ---------------------------------------------------------------------------
// Kernel 1: csum[d] = sum_m C[m, d]
// ---------------------------------------------------------------------------
__global__ void csum_kernel(const float* __restrict__ C, float* __restrict__ csum) {
    int d    = threadIdx.x & 63;
    int mloc = threadIdx.x >> 6;
    int m0   = blockIdx.x * 64;
    float s = 0.f;
#pragma unroll
    for (int j = 0; j < 16; ++j)
        s += C[(m0 + j * 4 + mloc) * DS + d];
    __shared__ float red[4][64];
    red[mloc][d] = s;
    __syncthreads();
    if (threadIdx.x < 64) {
        float t = red[0][d] + red[1][d] + red[2][d] + red[3][d];
        atomicAdd(&csum[d], t);
    }
}

// ---------------------------------------------------------------------------
// Kernel 2: Ktl[l*DM + k] = sum_d csum[d] * exp(A[d]*dt[k]*l) * B[d, k]
// ---------------------------------------------------------------------------
__global__ void taps_kernel(const float* __restrict__ A, const float* __restrict__ B,
                            const float* __restrict__ log_dt,
                            const float* __restrict__ csum, float* __restrict__ Ktl) {
    int g = blockIdx.x * blockDim.x + threadIdx.x;
    int k = g & (DM - 1);
    int l = g >> 10;
    float dt = __expf(log_dt[k]);
    float fl = (float)l;
    float acc = 0.f;
#pragma unroll 8
    for (int d = 0; d < DS; ++d)
        acc += csum[d] * __expf(A[d] * dt * fl) * B[d * DM + k];
    Ktl[g] = acc;
}

// ---------------------------------------------------------------------------
// Main conv. Persistent-over-t block: circular 192-row LDS buffer, taps staged
// once, 64 new rows (16 KB) prefetched per step ahead of compute.
// y[b,t,k] = D[k]*u[b,t,k] + sum_l Kt[l,k]*u[b,t+31-l,k]
// Row a of u lives at LDS slot (a+32) % 192 (row stride 256 B).
// Step at base t: compute reads rows [t-32, t+95] (slots disjoint from the
// prefetch of rows [t+96, t+159]); barrier at step end orders the next
// prefetch's overwrite of dead slots against this step's reads.
// ---------------------------------------------------------------------------
__global__ __launch_bounds__(256, 2)
void conv_kernel(const float* __restrict__ u, const float* __restrict__ Ktl,
                 const float* __restrict__ D, float* __restrict__ y) {
    __shared__ __align__(16) float smem_u[CAP * TCH];   // 48 KB, row stride 256B
    __shared__ __align__(16) float smem_t[KS * TCH];    // 16 KB, row stride 256B

    int k0 = blockIdx.x * TCH;
    int ts = blockIdx.y * OUTB;
    int b  = blockIdx.z;

    int lane = threadIdx.x & 63;
    int wv   = threadIdx.x >> 6;

    const float* ub = u + (size_t)b * SEQ * DM + k0;

    // ---- stage taps once: 16 KB = 4 iters x 4KB ----
#pragma unroll
    for (int j = 0; j < 4; ++j) {
        int fb = j * 4096 + wv * 1024;          // wave-uniform byte offset
        int f  = fb + lane * 16;
        int l  = f >> 8;
        int c  = (f & 255) >> 2;
        async_cp16(Ktl + l * DM + k0 + c, (char*)smem_t + fb);
    }

    // ---- initial u fill: rows [ts-32, ts+95] as two 64-row chunks ----
    {
        int A0 = ts - 32;
        int sb0 = (A0 + 32) % CAP;              // multiple of 64
        if (A0 >= 0) {
#pragma unroll
            for (int j = 0; j < 4; ++j) {
                int fb = j * 4096 + wv * 1024;
                int f  = fb + lane * 16;
                int r  = f >> 8;
                int c  = (f & 255) >> 2;
                async_cp16(ub + (size_t)(A0 + r) * DM + c,
                           (char*)smem_u + sb0 * 256 + fb);
            }
        } else {                                 // first t-partition: zero-fill t<0
#pragma unroll
            for (int j = 0; j < 4; ++j) {
                int f = j * 4096 + threadIdx.x * 16;
                int r = f >> 8;
                int c = (f & 255) >> 2;
                int t = A0 + r;
                float4 v = make_float4(0.f, 0.f, 0.f, 0.f);
                if (t >= 0)
                    v = *(const float4*)(ub + (size_t)t * DM + c);
                *(float4*)((char*)smem_u + sb0 * 256 + f) = v;
            }
        }
        int A1 = ts + 32;                        // always fully in-bounds
        int sb1 = (A1 + 32) % CAP;
#pragma unroll
        for (int j = 0; j < 4; ++j) {
            int fb = j * 4096 + wv * 1024;
            int f  = fb + lane * 16;
            int r  = f >> 8;
            int c  = (f & 255) >> 2;
            async_cp16(ub + (size_t)(A1 + r) * DM + c,
                       (char*)smem_u + sb1 * 256 + fb);
        }
    }
    __syncthreads();

    int c2 = threadIdx.x & 31;          // channel-pair lane
    int tg = threadIdx.x >> 5;          // t-group 0..7

    const float2* us = (const float2*)smem_u;   // [slot][32]
    const float2* tp = (const float2*)smem_t;   // [l][32]
    float2 D2 = *(const float2*)(D + k0 + 2 * c2);

    float2* yb = (float2*)y + (size_t)b * SEQ * (DM / 2) + (k0 >> 1) + c2;

#pragma unroll 1
    for (int s = 0; s < NSTEP; ++s) {
        int t = ts + s * STEP;

        // ---- prefetch next 64 rows [t+96, t+159] (issued before compute) ----
        if (s < NSTEP - 1) {
            int A  = t + 96;
            int sb = (A + 32) % CAP;
            if (A + 63 < SEQ) {
#pragma unroll
                for (int j = 0; j < 4; ++j) {
                    int fb = j * 4096 + wv * 1024;
                    int f  = fb + lane * 16;
                    int r  = f >> 8;
                    int c  = (f & 255) >> 2;
                    async_cp16(ub + (size_t)(A + r) * DM + c,
                               (char*)smem_u + sb * 256 + fb);
                }
            } else {                             // last partition: zero-fill t>=SEQ
#pragma unroll
                for (int j = 0; j < 4; ++j) {
                    int f = j * 4096 + threadIdx.x * 16;
                    int r = f >> 8;
                    int c = (f & 255) >> 2;
                    int tt = A + r;
                    float4 v = make_float4(0.f, 0.f, 0.f, 0.f);
                    if (tt < SEQ)
                        v = *(const float4*)(ub + (size_t)tt * DM + c);
                    *(float4*)((char*)smem_u + sb * 256 + f) = v;
                }
            }
        }

        // ---- compute outputs [t, t+64): circular 16-slot register window ----
        int o0 = t + tg * R;

        float2 acc[R];
#pragma unroll
        for (int r = 0; r < R; ++r) acc[r] = make_float2(0.f, 0.f);

        // window w[m&15] holds u row a = o0 + m - 32; init m = 55..70
        float2 w[16];
        int sl = (o0 + 55) % CAP;               // slot of row o0+23
#pragma unroll
        for (int m = 55; m <= 70; ++m) {
            w[m & 15] = us[sl * 32 + c2];
            sl = (sl == CAP - 1) ? 0 : sl + 1;
        }
        int sp = (o0 + 54) % CAP;               // slot of row o0+22 (l=0 prefetch)

#pragma unroll
        for (int l = 0; l < 64; ++l) {
            float2 t2 = tp[l * 32 + c2];
#pragma unroll
            for (int r = 0; r < R; ++r) {
                float2 uv = w[(r + 63 - l) & 15];
                acc[r].x = fmaf(t2.x, uv.x, acc[r].x);
                acc[r].y = fmaf(t2.y, uv.y, acc[r].y);
            }
            if (l == 31) {   // window slots m = r+32 hold u[o0+r]: fold in D*u
#pragma unroll
                for (int r = 0; r < R; ++r) {
                    float2 uv = w[(r + 32) & 15];
                    acc[r].x = fmaf(D2.x, uv.x, acc[r].x);
                    acc[r].y = fmaf(D2.y, uv.y, acc[r].y);
                }
            }
            if (l <= 54) {   // slide window: row o0+22-l, used 9-16 iters later
                w[(54 - l) & 15] = us[sp * 32 + c2];
                sp = (sp == 0) ? CAP - 1 : sp - 1;
            }
        }

        float2* yp = yb + (size_t)o0 * (DM / 2);
#pragma unroll
        for (int r = 0; r < R; ++r)
            yp[(size_t)r * (DM / 2)] = acc[r];

        __syncthreads();   // drains prefetch (vmcnt) + orders slot reuse
    }
}

// ---------------------------------------------------------------------------
extern "C" void kernel_launch(void* const* d_in, const int* in_sizes, int n_in,
                              void* d_out, int out_size, void* d_ws, size_t ws_size,
                              hipStream_t stream) {
    const float* u      = (const float*)d_in[0];
    const float* A      = (const float*)d_in[1];
    const float* Bp     = (const float*)d_in[2];
    const float* Cp     = (const float*)d_in[3];
    const float* Dp     = (const float*)d_in[4];
    const float* log_dt = (const float*)d_in[5];
    float* y = (float*)d_out;

    float* csum = (float*)d_ws;            // 64 floats
    float* Ktl  = csum + 64;               // 65536 floats, [l][k]

    hipMemsetAsync(csum, 0, DS * sizeof(float), stream);
    csum_kernel<<<16, 256, 0, stream>>>(Cp, csum);
    taps_kernel<<<(DM * KS) / 256, 256, 0, stream>>>(A, Bp, log_dt, csum, Ktl);

    dim3 grid(DM / TCH, SEQ / OUTB, 8);
    conv_kernel<<<grid, 256, 0, stream>>>(u, Ktl, Dp, y);
}